// Round 9
// baseline (237.138 us; speedup 1.0000x reference)
//
#include <hip/hip_runtime.h>
#include <hip/hip_bf16.h>

#define IN_CH 64
#define HC 128          // HEADS * OUT_CH
#define HEADS 8
#define OUT_CH 16
#define NEG 0.2f
#define PROJ_BLOCKS 1024
#define PROJ_NPI 16     // nodes per iteration per block

#define BK_BITS 10
#define BK_SIZE 1024    // nodes per bucket
#define BK_CAP 18432    // padded capacity per bucket (mean 16384, 16-sigma margin)
#define BIN_CHUNK 4096  // edges per b3 block

__device__ __forceinline__ float lrelu(float x) {
    return fmaxf(x, NEG * x);   // valid for NEG<1
}
__device__ __forceinline__ float bf2f(unsigned short u) {
    return __uint_as_float((unsigned)u << 16);
}

// ---- projection: persistent blocks, W staged once, x double-buffered ----
__global__ __launch_bounds__(256, 4) void proj_kernel(
    const float* __restrict__ x, const float* __restrict__ W,
    const float* __restrict__ att_src, const float* __restrict__ att_dst,
    __hip_bfloat16* __restrict__ hb, float* __restrict__ asrc,
    float* __restrict__ adst, int n)
{
    __shared__ float sWt[HC * IN_CH];        // 32 KB, transposed + swizzled
    __shared__ float sx[PROJ_NPI * IN_CH];   // 4 KB
    int tid = threadIdx.x;

    for (int idx = tid; idx < IN_CH * HC; idx += 256) {
        int k = idx >> 7, col = idx & 127;
        int slot = (k >> 2) ^ ((col >> 1) & 15);
        sWt[col * IN_CH + slot * 4 + (k & 3)] = W[idx];
    }

    int cp = tid & 63;       // col pair: cols 2cp, 2cp+1
    int ng = tid >> 6;       // wave id: nodes ng*4 .. ng*4+3
    int swz = cp & 15;
    int nl = tid >> 4;       // node-local index for x staging

    float as0 = att_src[2 * cp], as1 = att_src[2 * cp + 1];
    float ad0 = att_dst[2 * cp], ad1 = att_dst[2 * cp + 1];
    int head = cp >> 3;

    const float4* sW4 = (const float4*)sWt;
    const float4* sx4 = (const float4*)sx;
    unsigned* hbu = (unsigned*)hb;

    const int stride = PROJ_BLOCKS * PROJ_NPI;
    int node0 = blockIdx.x * PROJ_NPI;

    float4 xreg = make_float4(0.f, 0.f, 0.f, 0.f);
    if (node0 < n && node0 + nl < n)
        xreg = ((const float4*)(x + (long long)node0 * IN_CH))[tid];

    __syncthreads();   // W staged

    for (; node0 < n; node0 += stride) {
        ((float4*)sx)[tid] = xreg;
        __syncthreads();   // sx ready

        int next = node0 + stride;   // prefetch next x tile into registers
        if (next < n && next + nl < n)
            xreg = ((const float4*)(x + (long long)next * IN_CH))[tid];

        float acc[4][2];
        #pragma unroll
        for (int i = 0; i < 4; ++i) acc[i][0] = acc[i][1] = 0.f;

        #pragma unroll 4
        for (int k4 = 0; k4 < 16; ++k4) {
            float4 w0 = sW4[(2 * cp) * 16 + (k4 ^ swz)];
            float4 w1 = sW4[(2 * cp + 1) * 16 + (k4 ^ swz)];
            #pragma unroll
            for (int i = 0; i < 4; ++i) {
                float4 xv = sx4[(ng * 4 + i) * 16 + k4];
                acc[i][0] = fmaf(xv.x, w0.x, fmaf(xv.y, w0.y,
                            fmaf(xv.z, w0.z, fmaf(xv.w, w0.w, acc[i][0]))));
                acc[i][1] = fmaf(xv.x, w1.x, fmaf(xv.y, w1.y,
                            fmaf(xv.z, w1.z, fmaf(xv.w, w1.w, acc[i][1]))));
            }
        }

        #pragma unroll
        for (int i = 0; i < 4; ++i) {
            int node = node0 + ng * 4 + i;
            if (node < n) {
                __hip_bfloat16 b0 = __float2bfloat16(acc[i][0]);
                __hip_bfloat16 b1 = __float2bfloat16(acc[i][1]);
                unsigned pk = (unsigned)*(unsigned short*)&b0
                            | ((unsigned)*(unsigned short*)&b1 << 16);
                hbu[(long long)node * 64 + cp] = pk;

                float vs = acc[i][0] * as0 + acc[i][1] * as1;
                float vd = acc[i][0] * ad0 + acc[i][1] * ad1;
                #pragma unroll
                for (int m = 4; m >= 1; m >>= 1) {
                    vs += __shfl_xor(vs, m, 64);
                    vd += __shfl_xor(vd, m, 64);
                }
                if ((cp & 7) == 0) {
                    asrc[node * HEADS + head] = vs;
                    adst[node * HEADS + head] = vd;
                }
            }
        }
        __syncthreads();   // protect sx before next store
    }
}

// ---- bucketed CSR build (fixed-capacity padded buckets) ----
__global__ void cinit_kernel(int* __restrict__ cursor, int nbuck)
{
    int t = threadIdx.x;
    if (t < nbuck) cursor[t] = t * BK_CAP;
}

__global__ __launch_bounds__(256) void b3_bin(
    const int* __restrict__ ei, int E, int nbuck,
    int* __restrict__ cursor, unsigned* __restrict__ binned)
{
    __shared__ int cnt[256];
    __shared__ int resv[256];
    int tid = threadIdx.x;
    int chunk0 = blockIdx.x * BIN_CHUNK;
    cnt[tid] = 0;
    __syncthreads();
    for (int i = tid; i < BIN_CHUNK; i += 256) {
        int e = chunk0 + i;
        if (e < E) atomicAdd(&cnt[ei[E + e] >> BK_BITS], 1);
    }
    __syncthreads();
    if (tid < nbuck) resv[tid] = cnt[tid] ? atomicAdd(&cursor[tid], cnt[tid]) : 0;
    __syncthreads();
    for (int i = tid; i < BIN_CHUNK; i += 256) {
        int e = chunk0 + i;
        if (e < E) {
            int s = ei[e], d = ei[E + e];
            int b = d >> BK_BITS;
            int p = atomicAdd(&resv[b], 1);
            binned[p] = (unsigned)s | ((unsigned)(d & (BK_SIZE - 1)) << 20);
        }
    }
}

__global__ __launch_bounds__(256) void b4_build(
    const unsigned* __restrict__ binned, const int* __restrict__ cursor,
    int2* __restrict__ row2, int* __restrict__ csr, int n)
{
    __shared__ int deg[BK_SIZE];
    __shared__ int off[BK_SIZE];
    __shared__ int ts[256];
    int tid = threadIdx.x;
    int b = blockIdx.x;
    int node0 = b << BK_BITS;
    int nn = min(BK_SIZE, n - node0);
    int e0 = b * BK_CAP;
    int e1 = cursor[b];     // final cursor = e0 + bucket count

    for (int i = tid; i < BK_SIZE; i += 256) deg[i] = 0;
    __syncthreads();
    for (int j = e0 + tid; j < e1; j += 256)
        atomicAdd(&deg[binned[j] >> 20], 1);
    __syncthreads();

    int base4 = tid * 4;
    int v0 = deg[base4], v1 = deg[base4 + 1], v2 = deg[base4 + 2], v3 = deg[base4 + 3];
    int ssum = v0 + v1 + v2 + v3;
    ts[tid] = ssum;
    __syncthreads();
    for (int o = 1; o < 256; o <<= 1) {
        int xv = (tid >= o) ? ts[tid - o] : 0;
        __syncthreads();
        ts[tid] += xv;
        __syncthreads();
    }
    int run = ts[tid] - ssum;
    off[base4 + 0] = run;
    if (base4 + 0 < nn) row2[node0 + base4 + 0] = make_int2(e0 + run, e0 + run + v0);
    run += v0;
    off[base4 + 1] = run;
    if (base4 + 1 < nn) row2[node0 + base4 + 1] = make_int2(e0 + run, e0 + run + v1);
    run += v1;
    off[base4 + 2] = run;
    if (base4 + 2 < nn) row2[node0 + base4 + 2] = make_int2(e0 + run, e0 + run + v2);
    run += v2;
    off[base4 + 3] = run;
    if (base4 + 3 < nn) row2[node0 + base4 + 3] = make_int2(e0 + run, e0 + run + v3);
    __syncthreads();

    for (int i = tid; i < BK_SIZE; i += 256) deg[i] = off[i];
    __syncthreads();
    for (int j = e0 + tid; j < e1; j += 256) {
        unsigned pk = binned[j];
        int dl = pk >> 20;
        int s = (int)(pk & 0xFFFFFu);
        int p = atomicAdd(&deg[dl], 1);
        csr[e0 + p] = s;
    }
}

// ---- fused softmax + aggregation, batched-8-edge scheme ----
// Lane (eo=lane>>3, hA=lane&7) computes exp for edge j0+eo / head hA: one
// csr load + one asrc gather + one exp per 8 edges (was 8x each). h-row base
// via readlane -> SGPR: global_load with precomputed per-lane voffset, no
// per-edge vector address math.
__global__ __launch_bounds__(256) void agg_kernel(
    const int* __restrict__ csr, const int2* __restrict__ row2,
    const float* __restrict__ asrc, const float* __restrict__ adst,
    const __hip_bfloat16* __restrict__ hb, const float* __restrict__ bias,
    float* __restrict__ out, int n)
{
    int wave = threadIdx.x >> 6;
    int lane = threadIdx.x & 63;
    int d = blockIdx.x * 4 + wave;
    if (d >= n) return;

    int hA = lane & 7;          // head this lane computes exp for (phase A)
    int hO = lane >> 3;         // head owning this lane's output cols
    int eo = hO;                // edge offset within batch (lane>>3)
    int bidx = hO * 4;          // ds_bpermute byte base: source lane j*8+hO

    int2 se2 = row2[d];
    int start = se2.x, end = se2.y;

    float adstv = adst[d * HEADS + hA];
    const unsigned* hu = (const unsigned*)hb;

    // self loop: lane hO's value (eo==0 group computed head hA=hO... use
    // bpermute from lane hO which computed head hO)
    float ps = __expf(lrelu(asrc[d * HEADS + hA] + adstv));
    float w = __uint_as_float(__builtin_amdgcn_ds_bpermute(bidx, __float_as_uint(ps)));
    unsigned u = hu[(long long)d * 64 + lane];
    float denom = w;
    float accx = w * __uint_as_float(u << 16);
    float accy = w * __uint_as_float(u & 0xFFFF0000u);

    for (int j0 = start; j0 < end; j0 += 8) {
        // phase A: 8 edges' exp in one pass
        int idx = j0 + eo;
        int t = csr[idx];                       // padded alloc: in-bounds
        int se = (idx < end) ? t : 0;
        float a = asrc[se * HEADS + hA] + adstv;
        float pl = (idx < end) ? __expf(lrelu(a)) : 0.f;

        int nv = end - j0;                      // >=1
        // phase B: consume up to 8 edges
        #pragma unroll
        for (int j = 0; j < 8; ++j) {
            if (j < nv) {
                float wj = __uint_as_float(
                    __builtin_amdgcn_ds_bpermute(bidx + j * 32, __float_as_uint(pl)));
                int sj = __builtin_amdgcn_readlane(se, j * 8);   // uniform
                const unsigned* hrow = hu + (long long)sj * 64;
                unsigned uj = hrow[lane];
                denom += wj;
                accx = fmaf(wj, __uint_as_float(uj << 16), accx);
                accy = fmaf(wj, __uint_as_float(uj & 0xFFFF0000u), accy);
            }
        }
    }

    float inv = 1.f / (denom + 1e-16f);
    const float2* b2 = (const float2*)bias;
    float2 bb = b2[lane];
    float2 o;
    o.x = fmaxf(fmaf(accx, inv, bb.x), 0.f);
    o.y = fmaxf(fmaf(accy, inv, bb.y), 0.f);
    ((float2*)out)[(long long)d * 64 + lane] = o;
}

extern "C" void kernel_launch(void* const* d_in, const int* in_sizes, int n_in,
                              void* d_out, int out_size, void* d_ws, size_t ws_size,
                              hipStream_t stream) {
    const float* x       = (const float*)d_in[0];
    const float* W       = (const float*)d_in[1];
    const float* att_src = (const float*)d_in[2];
    const float* att_dst = (const float*)d_in[3];
    const float* bias    = (const float*)d_in[4];
    const int*   ei      = (const int*)d_in[5];

    int n = in_sizes[0] / IN_CH;        // 100000
    int E = in_sizes[5] / 2;            // 1600000
    float* out = (float*)d_out;
    int nbuck = (n + BK_SIZE - 1) >> BK_BITS;   // 98 (<=256 required)

    // workspace layout
    char* ws = (char*)d_ws;
    __hip_bfloat16* hb = (__hip_bfloat16*)ws; ws += (size_t)n * HC * 2;  // 25.6 MB
    float* asrc = (float*)ws;   ws += (size_t)n * HEADS * 4;             // 3.2 MB
    float* adst = (float*)ws;   ws += (size_t)n * HEADS * 4;             // 3.2 MB
    int*   csr  = (int*)ws;     ws += ((size_t)nbuck * BK_CAP + 64) * 4; // 7.2 MB
    unsigned* binned = (unsigned*)ws; ws += (size_t)nbuck * BK_CAP * 4;  // 7.2 MB
    int2*  row2 = (int2*)ws;    ws += (size_t)n * 8;                     // 0.8 MB
    int*   cursor=(int*)ws;     ws += 256 * 4;

    proj_kernel<<<PROJ_BLOCKS, 256, 0, stream>>>(x, W, att_src, att_dst,
                                                 hb, asrc, adst, n);

    cinit_kernel<<<1, 256, 0, stream>>>(cursor, nbuck);
    int binblk = (E + BIN_CHUNK - 1) / BIN_CHUNK;
    b3_bin<<<binblk, 256, 0, stream>>>(ei, E, nbuck, cursor, binned);
    b4_build<<<nbuck, 256, 0, stream>>>(binned, cursor, row2, csr, n);

    int ablk = (n + 3) / 4;
    agg_kernel<<<ablk, 256, 0, stream>>>(csr, row2, asrc, adst, hb, bias, out, n);
}

// Round 10
// 201.459 us; speedup vs baseline: 1.1771x; 1.1771x over previous
//
#include <hip/hip_runtime.h>
#include <hip/hip_bf16.h>

#define IN_CH 64
#define HC 128          // HEADS * OUT_CH
#define HEADS 8
#define OUT_CH 16
#define NEG 0.2f
#define PROJ_BLOCKS 1024
#define PROJ_NPI 16     // nodes per iteration per block

#define BK_BITS 10
#define BK_SIZE 1024    // nodes per bucket
#define BK_CAP 18432    // padded capacity per bucket (mean 16384, 16-sigma margin)
#define BIN_CHUNK 4096  // edges per b3 block

__device__ __forceinline__ float lrelu(float x) {
    return fmaxf(x, NEG * x);   // valid for NEG<1
}

// ---- projection: persistent blocks, W staged once, x double-buffered ----
__global__ __launch_bounds__(256, 4) void proj_kernel(
    const float* __restrict__ x, const float* __restrict__ W,
    const float* __restrict__ att_src, const float* __restrict__ att_dst,
    __hip_bfloat16* __restrict__ hb, float* __restrict__ asrc,
    float* __restrict__ adst, int n)
{
    __shared__ float sWt[HC * IN_CH];        // 32 KB, transposed + swizzled
    __shared__ float sx[PROJ_NPI * IN_CH];   // 4 KB
    int tid = threadIdx.x;

    for (int idx = tid; idx < IN_CH * HC; idx += 256) {
        int k = idx >> 7, col = idx & 127;
        int slot = (k >> 2) ^ ((col >> 1) & 15);
        sWt[col * IN_CH + slot * 4 + (k & 3)] = W[idx];
    }

    int cp = tid & 63;       // col pair: cols 2cp, 2cp+1
    int ng = tid >> 6;       // wave id: nodes ng*4 .. ng*4+3
    int swz = cp & 15;
    int nl = tid >> 4;       // node-local index for x staging

    float as0 = att_src[2 * cp], as1 = att_src[2 * cp + 1];
    float ad0 = att_dst[2 * cp], ad1 = att_dst[2 * cp + 1];
    int head = cp >> 3;

    const float4* sW4 = (const float4*)sWt;
    const float4* sx4 = (const float4*)sx;
    unsigned* hbu = (unsigned*)hb;

    const int stride = PROJ_BLOCKS * PROJ_NPI;
    int node0 = blockIdx.x * PROJ_NPI;

    float4 xreg = make_float4(0.f, 0.f, 0.f, 0.f);
    if (node0 < n && node0 + nl < n)
        xreg = ((const float4*)(x + (long long)node0 * IN_CH))[tid];

    __syncthreads();   // W staged

    for (; node0 < n; node0 += stride) {
        ((float4*)sx)[tid] = xreg;
        __syncthreads();   // sx ready

        int next = node0 + stride;   // prefetch next x tile into registers
        if (next < n && next + nl < n)
            xreg = ((const float4*)(x + (long long)next * IN_CH))[tid];

        float acc[4][2];
        #pragma unroll
        for (int i = 0; i < 4; ++i) acc[i][0] = acc[i][1] = 0.f;

        #pragma unroll 4
        for (int k4 = 0; k4 < 16; ++k4) {
            float4 w0 = sW4[(2 * cp) * 16 + (k4 ^ swz)];
            float4 w1 = sW4[(2 * cp + 1) * 16 + (k4 ^ swz)];
            #pragma unroll
            for (int i = 0; i < 4; ++i) {
                float4 xv = sx4[(ng * 4 + i) * 16 + k4];
                acc[i][0] = fmaf(xv.x, w0.x, fmaf(xv.y, w0.y,
                            fmaf(xv.z, w0.z, fmaf(xv.w, w0.w, acc[i][0]))));
                acc[i][1] = fmaf(xv.x, w1.x, fmaf(xv.y, w1.y,
                            fmaf(xv.z, w1.z, fmaf(xv.w, w1.w, acc[i][1]))));
            }
        }

        #pragma unroll
        for (int i = 0; i < 4; ++i) {
            int node = node0 + ng * 4 + i;
            if (node < n) {
                __hip_bfloat16 b0 = __float2bfloat16(acc[i][0]);
                __hip_bfloat16 b1 = __float2bfloat16(acc[i][1]);
                unsigned pk = (unsigned)*(unsigned short*)&b0
                            | ((unsigned)*(unsigned short*)&b1 << 16);
                hbu[(long long)node * 64 + cp] = pk;

                float vs = acc[i][0] * as0 + acc[i][1] * as1;
                float vd = acc[i][0] * ad0 + acc[i][1] * ad1;
                #pragma unroll
                for (int m = 4; m >= 1; m >>= 1) {
                    vs += __shfl_xor(vs, m, 64);
                    vd += __shfl_xor(vd, m, 64);
                }
                if ((cp & 7) == 0) {
                    asrc[node * HEADS + head] = vs;
                    adst[node * HEADS + head] = vd;
                }
            }
        }
        __syncthreads();   // protect sx before next store
    }
}

// ---- bucketed CSR build (fixed-capacity padded buckets) ----
__global__ void cinit_kernel(int* __restrict__ cursor, int nbuck)
{
    int t = threadIdx.x;
    if (t < nbuck) cursor[t] = t * BK_CAP;
}

__global__ __launch_bounds__(256) void b3_bin(
    const int* __restrict__ ei, int E, int nbuck,
    int* __restrict__ cursor, unsigned* __restrict__ binned)
{
    __shared__ int cnt[256];
    __shared__ int resv[256];
    int tid = threadIdx.x;
    int chunk0 = blockIdx.x * BIN_CHUNK;
    cnt[tid] = 0;
    __syncthreads();
    for (int i = tid; i < BIN_CHUNK; i += 256) {
        int e = chunk0 + i;
        if (e < E) atomicAdd(&cnt[ei[E + e] >> BK_BITS], 1);
    }
    __syncthreads();
    if (tid < nbuck) resv[tid] = cnt[tid] ? atomicAdd(&cursor[tid], cnt[tid]) : 0;
    __syncthreads();
    for (int i = tid; i < BIN_CHUNK; i += 256) {
        int e = chunk0 + i;
        if (e < E) {
            int s = ei[e], d = ei[E + e];
            int b = d >> BK_BITS;
            int p = atomicAdd(&resv[b], 1);
            binned[p] = (unsigned)s | ((unsigned)(d & (BK_SIZE - 1)) << 20);
        }
    }
}

__global__ __launch_bounds__(256) void b4_build(
    const unsigned* __restrict__ binned, const int* __restrict__ cursor,
    int2* __restrict__ row2, int* __restrict__ csr, int n)
{
    __shared__ int deg[BK_SIZE];
    __shared__ int off[BK_SIZE];
    __shared__ int ts[256];
    int tid = threadIdx.x;
    int b = blockIdx.x;
    int node0 = b << BK_BITS;
    int nn = min(BK_SIZE, n - node0);
    int e0 = b * BK_CAP;
    int e1 = cursor[b];     // final cursor = e0 + bucket count

    for (int i = tid; i < BK_SIZE; i += 256) deg[i] = 0;
    __syncthreads();
    for (int j = e0 + tid; j < e1; j += 256)
        atomicAdd(&deg[binned[j] >> 20], 1);
    __syncthreads();

    int base4 = tid * 4;
    int v0 = deg[base4], v1 = deg[base4 + 1], v2 = deg[base4 + 2], v3 = deg[base4 + 3];
    int ssum = v0 + v1 + v2 + v3;
    ts[tid] = ssum;
    __syncthreads();
    for (int o = 1; o < 256; o <<= 1) {
        int xv = (tid >= o) ? ts[tid - o] : 0;
        __syncthreads();
        ts[tid] += xv;
        __syncthreads();
    }
    int run = ts[tid] - ssum;
    off[base4 + 0] = run;
    if (base4 + 0 < nn) row2[node0 + base4 + 0] = make_int2(e0 + run, e0 + run + v0);
    run += v0;
    off[base4 + 1] = run;
    if (base4 + 1 < nn) row2[node0 + base4 + 1] = make_int2(e0 + run, e0 + run + v1);
    run += v1;
    off[base4 + 2] = run;
    if (base4 + 2 < nn) row2[node0 + base4 + 2] = make_int2(e0 + run, e0 + run + v2);
    run += v2;
    off[base4 + 3] = run;
    if (base4 + 3 < nn) row2[node0 + base4 + 3] = make_int2(e0 + run, e0 + run + v3);
    __syncthreads();

    for (int i = tid; i < BK_SIZE; i += 256) deg[i] = off[i];
    __syncthreads();
    for (int j = e0 + tid; j < e1; j += 256) {
        unsigned pk = binned[j];
        int dl = pk >> 20;
        int s = (int)(pk & 0xFFFFFu);
        int p = atomicAdd(&deg[dl], 1);
        csr[e0 + p] = s;
    }
}

// ---- fused softmax + aggregation: own-head exp, NO cross-lane ops ----
// Lane owns cols (2l,2l+1), head hO=l>>3. Lane computes exp for its own head
// directly (8-lane groups read same 4B -> HW broadcast; redundant exp is free
// in SIMD). Removes the per-edge ds_bpermute of rounds 7/9: no lgkm waits in
// the loop, 4 independent gather chains in flight.
__global__ __launch_bounds__(256) void agg_kernel(
    const int* __restrict__ csr, const int2* __restrict__ row2,
    const float* __restrict__ asrc, const float* __restrict__ adst,
    const __hip_bfloat16* __restrict__ hb, const float* __restrict__ bias,
    float* __restrict__ out, int n)
{
    int wave = threadIdx.x >> 6;
    int lane = threadIdx.x & 63;
    int d = blockIdx.x * 4 + wave;
    if (d >= n) return;

    int hO = lane >> 3;         // head owning this lane's output cols

    int2 se = row2[d];
    int start = se.x, end = se.y;

    float adstv = adst[d * HEADS + hO];
    const unsigned* hu = (const unsigned*)hb;

    // self loop
    float w = __expf(lrelu(asrc[d * HEADS + hO] + adstv));
    unsigned u = hu[(long long)d * 64 + lane];
    float denom = w;
    float accx = w * __uint_as_float(u << 16);
    float accy = w * __uint_as_float(u & 0xFFFF0000u);

    int j = start;
    for (; j + 3 < end; j += 4) {
        int s0 = csr[j], s1 = csr[j + 1], s2 = csr[j + 2], s3 = csr[j + 3];
        float w0 = __expf(lrelu(asrc[s0 * HEADS + hO] + adstv));
        float w1 = __expf(lrelu(asrc[s1 * HEADS + hO] + adstv));
        float w2 = __expf(lrelu(asrc[s2 * HEADS + hO] + adstv));
        float w3 = __expf(lrelu(asrc[s3 * HEADS + hO] + adstv));
        unsigned u0 = hu[(long long)s0 * 64 + lane];
        unsigned u1 = hu[(long long)s1 * 64 + lane];
        unsigned u2 = hu[(long long)s2 * 64 + lane];
        unsigned u3 = hu[(long long)s3 * 64 + lane];
        denom += (w0 + w1) + (w2 + w3);
        accx = fmaf(w0, __uint_as_float(u0 << 16), accx);
        accy = fmaf(w0, __uint_as_float(u0 & 0xFFFF0000u), accy);
        accx = fmaf(w1, __uint_as_float(u1 << 16), accx);
        accy = fmaf(w1, __uint_as_float(u1 & 0xFFFF0000u), accy);
        accx = fmaf(w2, __uint_as_float(u2 << 16), accx);
        accy = fmaf(w2, __uint_as_float(u2 & 0xFFFF0000u), accy);
        accx = fmaf(w3, __uint_as_float(u3 << 16), accx);
        accy = fmaf(w3, __uint_as_float(u3 & 0xFFFF0000u), accy);
    }
    for (; j < end; ++j) {
        int s0 = csr[j];
        float w0 = __expf(lrelu(asrc[s0 * HEADS + hO] + adstv));
        unsigned u0 = hu[(long long)s0 * 64 + lane];
        denom += w0;
        accx = fmaf(w0, __uint_as_float(u0 << 16), accx);
        accy = fmaf(w0, __uint_as_float(u0 & 0xFFFF0000u), accy);
    }

    float inv = 1.f / (denom + 1e-16f);
    const float2* b2 = (const float2*)bias;
    float2 bb = b2[lane];
    float2 o;
    o.x = fmaxf(fmaf(accx, inv, bb.x), 0.f);
    o.y = fmaxf(fmaf(accy, inv, bb.y), 0.f);
    ((float2*)out)[(long long)d * 64 + lane] = o;
}

extern "C" void kernel_launch(void* const* d_in, const int* in_sizes, int n_in,
                              void* d_out, int out_size, void* d_ws, size_t ws_size,
                              hipStream_t stream) {
    const float* x       = (const float*)d_in[0];
    const float* W       = (const float*)d_in[1];
    const float* att_src = (const float*)d_in[2];
    const float* att_dst = (const float*)d_in[3];
    const float* bias    = (const float*)d_in[4];
    const int*   ei      = (const int*)d_in[5];

    int n = in_sizes[0] / IN_CH;        // 100000
    int E = in_sizes[5] / 2;            // 1600000
    float* out = (float*)d_out;
    int nbuck = (n + BK_SIZE - 1) >> BK_BITS;   // 98 (<=256 required)

    // workspace layout
    char* ws = (char*)d_ws;
    __hip_bfloat16* hb = (__hip_bfloat16*)ws; ws += (size_t)n * HC * 2;  // 25.6 MB
    float* asrc = (float*)ws;   ws += (size_t)n * HEADS * 4;             // 3.2 MB
    float* adst = (float*)ws;   ws += (size_t)n * HEADS * 4;             // 3.2 MB
    int*   csr  = (int*)ws;     ws += ((size_t)nbuck * BK_CAP + 64) * 4; // 7.2 MB
    unsigned* binned = (unsigned*)ws; ws += (size_t)nbuck * BK_CAP * 4;  // 7.2 MB
    int2*  row2 = (int2*)ws;    ws += (size_t)n * 8;                     // 0.8 MB
    int*   cursor=(int*)ws;     ws += 256 * 4;

    proj_kernel<<<PROJ_BLOCKS, 256, 0, stream>>>(x, W, att_src, att_dst,
                                                 hb, asrc, adst, n);

    cinit_kernel<<<1, 256, 0, stream>>>(cursor, nbuck);
    int binblk = (E + BIN_CHUNK - 1) / BIN_CHUNK;
    b3_bin<<<binblk, 256, 0, stream>>>(ei, E, nbuck, cursor, binned);
    b4_build<<<nbuck, 256, 0, stream>>>(binned, cursor, row2, csr, n);

    int ablk = (n + 3) / 4;
    agg_kernel<<<ablk, 256, 0, stream>>>(csr, row2, asrc, adst, hb, bias, out, n);
}